// Round 8
// baseline (554.092 us; speedup 1.0000x reference)
//
#include <hip/hip_runtime.h>
#include <math.h>

#define HWP 4096
#define CCH 256
#define NN  1024
#define DD  256
#define ZQ_SIZE (8 * DD * HWP)       // 8388608 floats
#define MARGIN 2e-3f                 // 2-product screening: gap-err std 1.3e-4 -> 15 sigma
#define WLCAP 4096
#define PXB 8                        // fixup pixels per group

typedef _Float16 h8 __attribute__((ext_vector_type(8)));
typedef float    f4 __attribute__((ext_vector_type(4)));

// ---------- K1: w -> fp16 (hi only), SWIZZLED fragment order ----------
// whS: [r16 0..63][kc 0..7][lane 0..63][j 0..7] halfs.
__global__ __launch_bounds__(256) void split_w_k(
    const float* __restrict__ w, _Float16* __restrict__ whS,
    int* __restrict__ wcount)
{
    if (blockIdx.x == 0 && threadIdx.x == 0) *wcount = 0;
    const int t = blockIdx.x * 256 + threadIdx.x;
    const int l = t & 63;
    const int frag = t >> 6;
    const int kc = frag & 7, r16 = frag >> 3;
    const int row = r16 * 16 + (l & 15);
    const int c   = kc * 32 + (l >> 4) * 8;
    const float* src = w + (size_t)row * CCH + c;
    _Float16 hv[8];
#pragma unroll
    for (int j = 0; j < 8; ++j) hv[j] = (_Float16)src[j];
    *(h8*)(whS + (size_t)t * 8) = *(const h8*)hv;
}

// ---------- K2: fused z-split + 2-product MFMA GEMM + top2 + gather ----------
// VERBATIM R6 (proven 62.2 us, VGPR 56, spill-free, absmax 0).
__global__ __launch_bounds__(512, 4) void mfma_gemm_k(
    const float* __restrict__ z,
    const _Float16* __restrict__ whS,
    const float* __restrict__ bias, const float* __restrict__ embed,
    int* __restrict__ wcount, int* __restrict__ wlist,
    float* __restrict__ out)
{
    __shared__ __align__(16) char smem[71680];
    __shared__ int indsh2[64];
    float* s_best = (float*)(smem + 65536);     // [8][64]
    float* s_sec  = (float*)(smem + 67584);
    int*   s_idx  = (int*)  (smem + 69632);

    const int tid = threadIdx.x;
    const int l   = tid & 63;
    const int wv  = tid >> 6;                   // 0..7
    const int mh  = wv >> 2;                    // pixel half: px in [32*mh, 32*mh+32)
    const int ng  = wv & 3;                     // n-group
    const int c15 = l & 15, g = l >> 4;
    const int pix0 = blockIdx.x * 64;
    const int b = pix0 >> 12, p0 = pix0 & 4095;

    // ---- Stage A: z -> hi/lo fp16 frag-order LDS ----
    {
        const int px = tid & 63;
        const int wv2 = tid >> 6;                // 0..7
        const int p16 = px >> 4;
        const float* zb = z + (size_t)b * CCH * HWP + p0 + px;
#pragma unroll
        for (int it = 0; it < 4; ++it) {
            const int cg = wv2 * 4 + it;         // c-group of 8 (0..31)
            const int c = cg * 8;
            float xv[8];
#pragma unroll
            for (int i = 0; i < 8; ++i) xv[i] = zb[(size_t)(c + i) * HWP];
            _Float16 hv[8], lv[8];
#pragma unroll
            for (int i = 0; i < 8; ++i) {
                const _Float16 h = (_Float16)xv[i];
                hv[i] = h;
                lv[i] = (_Float16)(xv[i] - (float)h);
            }
            const int kc = cg >> 2;
            const int lane = (px & 15) + 16 * (cg & 3);
            const int off = ((p16 * 8 + kc) * 64 + lane) * 16;   // bytes, < 32768
            *(h8*)(smem + off)         = *(const h8*)hv;
            *(h8*)(smem + 32768 + off) = *(const h8*)lv;
        }
    }
    __syncthreads();

    float best[8], sec[8]; int bidx[8];
#pragma unroll
    for (int s = 0; s < 8; ++s) { best[s] = -INFINITY; sec[s] = -INFINITY; bidx[s] = 0; }

#pragma unroll 1
    for (int nt = 0; nt < 4; ++nt) {
        const int n0 = nt * 256 + ng * 64;
        const int r16_0 = n0 >> 4;
        f4 acc[2][4];
#pragma unroll
        for (int mf = 0; mf < 2; ++mf)
#pragma unroll
            for (int nf = 0; nf < 4; ++nf) acc[mf][nf] = (f4)0.f;

#pragma unroll 2
        for (int kc = 0; kc < 8; ++kc) {
            h8 ah[2], al[2], bh[4];
#pragma unroll
            for (int mf = 0; mf < 2; ++mf) {
                const int ao = (((mh * 2 + mf) * 8 + kc) * 64 + l) * 16;
                ah[mf] = *(const h8*)(smem + ao);
                al[mf] = *(const h8*)(smem + 32768 + ao);
            }
#pragma unroll
            for (int nf = 0; nf < 4; ++nf) {
                const size_t bo = (((size_t)(r16_0 + nf) * 8 + kc) * 64 + l) * 8;
                bh[nf] = *(const h8*)(whS + bo);
            }
#pragma unroll
            for (int mf = 0; mf < 2; ++mf)
#pragma unroll
                for (int nf = 0; nf < 4; ++nf) {
                    acc[mf][nf] = __builtin_amdgcn_mfma_f32_16x16x32_f16(ah[mf], bh[nf], acc[mf][nf], 0, 0, 0);
                    acc[mf][nf] = __builtin_amdgcn_mfma_f32_16x16x32_f16(al[mf], bh[nf], acc[mf][nf], 0, 0, 0);
                }
        }
#pragma unroll
        for (int nf = 0; nf < 4; ++nf) {
            const int n_abs = n0 + nf * 16 + c15;
            const float bv = bias[n_abs];
#pragma unroll
            for (int mf = 0; mf < 2; ++mf)
#pragma unroll
                for (int r = 0; r < 4; ++r) {
                    const float v = acc[mf][nf][r] + bv;
                    const int s = mf * 4 + r;
                    if (v > best[s]) { sec[s] = best[s]; best[s] = v; bidx[s] = n_abs; }
                    else if (v > sec[s]) sec[s] = v;
                }
        }
    }

#pragma unroll
    for (int d = 1; d < 16; d <<= 1) {
#pragma unroll
        for (int s = 0; s < 8; ++s) {
            const float ob = __shfl_xor(best[s], d, 64);
            const float os = __shfl_xor(sec[s], d, 64);
            const int   oi = __shfl_xor(bidx[s], d, 64);
            if (ob > best[s])       { sec[s] = fmaxf(best[s], os); best[s] = ob; bidx[s] = oi; }
            else if (ob == best[s]) { sec[s] = ob; bidx[s] = (oi < bidx[s]) ? oi : bidx[s]; }
            else                    { sec[s] = fmaxf(sec[s], ob); }
        }
    }
#pragma unroll
    for (int s = 0; s < 8; ++s) {
        if (c15 == s) {
            const int px = (mh * 2 + (s >> 2)) * 16 + g * 4 + (s & 3);
            s_best[wv * 64 + px] = best[s];
            s_sec [wv * 64 + px] = sec[s];
            s_idx [wv * 64 + px] = bidx[s];
        }
    }
    __syncthreads();
    if (tid < 64) {
        const int wb = (tid >> 5) * 4;
        float b0 = s_best[wb * 64 + tid], s0 = s_sec[wb * 64 + tid]; int i0 = s_idx[wb * 64 + tid];
#pragma unroll
        for (int c = 1; c < 4; ++c) {
            const float ob = s_best[(wb + c) * 64 + tid], os = s_sec[(wb + c) * 64 + tid];
            const int   oi = s_idx [(wb + c) * 64 + tid];
            if (ob > b0 || (ob == b0 && oi < i0)) { s0 = fmaxf(b0, os); b0 = ob; i0 = oi; }
            else                                  { s0 = fmaxf(s0, ob); }
        }
        const int pix = pix0 + tid;
        indsh2[tid] = i0;
        out[ZQ_SIZE + 1 + pix] = (float)i0;
        if (b0 - s0 < MARGIN) {
            const int pos = atomicAdd(wcount, 1);
            if (pos < WLCAP) wlist[pos] = pix;
        }
    }
    if (blockIdx.x == 0 && tid == 0) out[ZQ_SIZE] = 0.0f;
    __syncthreads();

    float (*tile)[257] = (float (*)[257])smem;
    const int lq = tid & 63, wq = tid >> 6;
    const int l32 = tid & 31, dq = tid >> 5;
#pragma unroll 1
    for (int pp = 0; pp < 2; ++pp) {
#pragma unroll
        for (int it = 0; it < 4; ++it) {
            const int pl = it * 8 + wq;
            const int row = indsh2[pp * 32 + pl];
            const float4 e = *(const float4*)(embed + (size_t)row * DD + lq * 4);
            tile[pl][lq * 4 + 0] = e.x;
            tile[pl][lq * 4 + 1] = e.y;
            tile[pl][lq * 4 + 2] = e.z;
            tile[pl][lq * 4 + 3] = e.w;
        }
        __syncthreads();
        float* outz = out + (size_t)b * DD * HWP + p0 + pp * 32;
#pragma unroll
        for (int dd = 0; dd < 16; ++dd) {
            const int d = dd * 16 + dq;
            outz[(size_t)d * HWP + l32] = tile[l32][d];
        }
        __syncthreads();
    }
}

// ---------- K3: exact-fp32 fixup — 8 px/group, 8 waves split the 1024 rows ----------
// R7 lesson: chunk tasks re-loaded z 8x -> 66 MB random HBM = the 77 us.
// R6 lesson: per-task serial w load->use chain (16 g16 x ~400cyc) = the 59 us.
// This version: z loaded ONCE per group; 512 thr, wave wv owns rows
// [wv*128, wv*128+128) -> 8 g16 iters; per g16 all 16 w-float4 batch-issued
// into regs BEFORE the FMA block (one ~400cyc wait instead of a chain).
// Self-contained tasks, no cross-block atomics.
__global__ __launch_bounds__(512) void fixup_k(
    const float* __restrict__ z, const float* __restrict__ w,
    const float* __restrict__ bias, const float* __restrict__ embed,
    const int* __restrict__ wcount, const int* __restrict__ wlist,
    float* __restrict__ out)
{
    __shared__ float zsh[PXB][256];
    __shared__ float m_v[8][PXB];
    __shared__ int   m_i[8][PXB];
    __shared__ int   s_idx[PXB];

    const int tid = threadIdx.x;
    const int l = tid & 63, wv = tid >> 6;      // 8 waves
    const int c15 = l & 15, q = l >> 4;
    int nw = *wcount;
    if (nw > WLCAP) nw = WLCAP;
    if (nw < 0) nw = 0;
    const int npg = (nw + PXB - 1) / PXB;

    for (int pg = blockIdx.x; pg < npg; pg += 512) {
        const int e0 = pg * PXB;
        const int npx = (nw - e0 < PXB) ? (nw - e0) : PXB;
        int pixv[PXB];
#pragma unroll
        for (int px = 0; px < PXB; ++px)
            pixv[px] = wlist[e0 + ((px < npx) ? px : (npx - 1))];

        __syncthreads();   // guard zsh/s_idx reuse across pg-iterations
        // z gather ONCE: 2048 scattered loads spread over 512 threads
#pragma unroll
        for (int it = 0; it < (PXB * 256) / 512; ++it) {
            const int i = it * 512 + tid;
            const int px = i >> 8, c = i & 255;
            const int pix = pixv[px];
            const int b = pix >> 12, p = pix & 4095;
            zsh[px][c] = z[((size_t)b * CCH + c) * HWP + p];
        }
        __syncthreads();

        float best[PXB]; int bi[PXB];
#pragma unroll
        for (int px = 0; px < PXB; ++px) { best[px] = -INFINITY; bi[px] = 0; }

#pragma unroll 1
        for (int g16 = 0; g16 < 8; ++g16) {
            const int row = wv * 128 + g16 * 16 + c15;
            const float* wr = w + (size_t)row * CCH + q * 64;
            float4 w4[16];
#pragma unroll
            for (int j = 0; j < 16; ++j) w4[j] = *(const float4*)(wr + j * 4);
            float part[PXB];
#pragma unroll
            for (int px = 0; px < PXB; ++px) part[px] = 0.f;
#pragma unroll
            for (int j = 0; j < 16; ++j) {
#pragma unroll
                for (int px = 0; px < PXB; ++px) {
                    const float4 z4 = *(const float4*)&zsh[px][q * 64 + j * 4];
                    part[px] = fmaf(w4[j].x, z4.x, part[px]);
                    part[px] = fmaf(w4[j].y, z4.y, part[px]);
                    part[px] = fmaf(w4[j].z, z4.z, part[px]);
                    part[px] = fmaf(w4[j].w, z4.w, part[px]);
                }
            }
            const float bv = bias[row];
#pragma unroll
            for (int px = 0; px < PXB; ++px) {
                float pv = part[px];
                pv += __shfl_xor(pv, 16, 64);
                pv += __shfl_xor(pv, 32, 64);
                const float v = pv + bv;
                if (v > best[px]) { best[px] = v; bi[px] = row; }   // row ascends -> min idx kept
            }
        }
        // butterfly over the 16 col-lanes
#pragma unroll
        for (int d = 1; d < 16; d <<= 1) {
#pragma unroll
            for (int px = 0; px < PXB; ++px) {
                const float ob = __shfl_xor(best[px], d, 64);
                const int   oi = __shfl_xor(bi[px], d, 64);
                if (ob > best[px] || (ob == best[px] && oi < bi[px])) { best[px] = ob; bi[px] = oi; }
            }
        }
        if (l == 0) {
#pragma unroll
            for (int px = 0; px < PXB; ++px) { m_v[wv][px] = best[px]; m_i[wv][px] = bi[px]; }
        }
        __syncthreads();
        if (tid < npx) {
            float v = m_v[0][tid]; int i = m_i[0][tid];
#pragma unroll
            for (int w2 = 1; w2 < 8; ++w2)
                if (m_v[w2][tid] > v || (m_v[w2][tid] == v && m_i[w2][tid] < i)) { v = m_v[w2][tid]; i = m_i[w2][tid]; }
            s_idx[tid] = i;
            out[ZQ_SIZE + 1 + pixv[tid]] = (float)i;
        }
        __syncthreads();
        // z_q rewrite: 2 px per pass across 512 threads
#pragma unroll
        for (int pp = 0; pp < PXB; pp += 2) {
            const int px = pp + (tid >> 8);
            const int d = tid & 255;
            if (px < npx) {
                const int pix = pixv[px];
                const int b = pix >> 12, p = pix & 4095;
                out[((size_t)b * DD + d) * HWP + p] = embed[(size_t)s_idx[px] * DD + d];
            }
        }
    }
}

extern "C" void kernel_launch(void* const* d_in, const int* in_sizes, int n_in,
                              void* d_out, int out_size, void* d_ws, size_t ws_size,
                              hipStream_t stream) {
    const float* z     = (const float*)d_in[0];
    const float* w     = (const float*)d_in[1];
    const float* bias  = (const float*)d_in[2];
    const float* embed = (const float*)d_in[3];
    float* out = (float*)d_out;

    // ws: whS 512K | wcount | wlist 16K
    _Float16* whS = (_Float16*)d_ws;
    int* wcount = (int*)((char*)d_ws + 524288);
    int* wlist  = (int*)((char*)d_ws + 524544);

    hipLaunchKernelGGL(split_w_k,   dim3(128), dim3(256), 0, stream, w, whS, wcount);
    hipLaunchKernelGGL(mfma_gemm_k, dim3(512), dim3(512), 0, stream,
                       z, whS, bias, embed, wcount, wlist, out);
    hipLaunchKernelGGL(fixup_k,     dim3(512), dim3(512), 0, stream,
                       z, w, bias, embed, wcount, wlist, out);
}

// Round 9
// 348.311 us; speedup vs baseline: 1.5908x; 1.5908x over previous
//
#include <hip/hip_runtime.h>
#include <math.h>

#define HWP 4096
#define CCH 256
#define NN  1024
#define DD  256
#define ZQ_SIZE (8 * DD * HWP)       // 8388608 floats
#define MARGIN 2e-3f                 // 2-product screening: gap-err std 1.3e-4 -> 15 sigma
#define WLCAP 4096
#define PXB 8                        // fixup pixels per group

typedef _Float16 h8 __attribute__((ext_vector_type(8)));
typedef float    f4 __attribute__((ext_vector_type(4)));

// ---------- K1: w -> fp16 (hi only), SWIZZLED fragment order ----------
// whS: [r16 0..63][kc 0..7][lane 0..63][j 0..7] halfs.
__global__ __launch_bounds__(256) void split_w_k(
    const float* __restrict__ w, _Float16* __restrict__ whS,
    int* __restrict__ wcount)
{
    if (blockIdx.x == 0 && threadIdx.x == 0) *wcount = 0;
    const int t = blockIdx.x * 256 + threadIdx.x;
    const int l = t & 63;
    const int frag = t >> 6;
    const int kc = frag & 7, r16 = frag >> 3;
    const int row = r16 * 16 + (l & 15);
    const int c   = kc * 32 + (l >> 4) * 8;
    const float* src = w + (size_t)row * CCH + c;
    _Float16 hv[8];
#pragma unroll
    for (int j = 0; j < 8; ++j) hv[j] = (_Float16)src[j];
    *(h8*)(whS + (size_t)t * 8) = *(const h8*)hv;
}

// ---------- K2: fused z-split + 2-product MFMA GEMM + top2 + gather ----------
// VERBATIM R6 (proven 62.2 us, VGPR 56, spill-free, absmax 0).
__global__ __launch_bounds__(512, 4) void mfma_gemm_k(
    const float* __restrict__ z,
    const _Float16* __restrict__ whS,
    const float* __restrict__ bias, const float* __restrict__ embed,
    int* __restrict__ wcount, int* __restrict__ wlist,
    float* __restrict__ out)
{
    __shared__ __align__(16) char smem[71680];
    __shared__ int indsh2[64];
    float* s_best = (float*)(smem + 65536);     // [8][64]
    float* s_sec  = (float*)(smem + 67584);
    int*   s_idx  = (int*)  (smem + 69632);

    const int tid = threadIdx.x;
    const int l   = tid & 63;
    const int wv  = tid >> 6;                   // 0..7
    const int mh  = wv >> 2;                    // pixel half: px in [32*mh, 32*mh+32)
    const int ng  = wv & 3;                     // n-group
    const int c15 = l & 15, g = l >> 4;
    const int pix0 = blockIdx.x * 64;
    const int b = pix0 >> 12, p0 = pix0 & 4095;

    // ---- Stage A: z -> hi/lo fp16 frag-order LDS ----
    {
        const int px = tid & 63;
        const int wv2 = tid >> 6;                // 0..7
        const int p16 = px >> 4;
        const float* zb = z + (size_t)b * CCH * HWP + p0 + px;
#pragma unroll
        for (int it = 0; it < 4; ++it) {
            const int cg = wv2 * 4 + it;         // c-group of 8 (0..31)
            const int c = cg * 8;
            float xv[8];
#pragma unroll
            for (int i = 0; i < 8; ++i) xv[i] = zb[(size_t)(c + i) * HWP];
            _Float16 hv[8], lv[8];
#pragma unroll
            for (int i = 0; i < 8; ++i) {
                const _Float16 h = (_Float16)xv[i];
                hv[i] = h;
                lv[i] = (_Float16)(xv[i] - (float)h);
            }
            const int kc = cg >> 2;
            const int lane = (px & 15) + 16 * (cg & 3);
            const int off = ((p16 * 8 + kc) * 64 + lane) * 16;   // bytes, < 32768
            *(h8*)(smem + off)         = *(const h8*)hv;
            *(h8*)(smem + 32768 + off) = *(const h8*)lv;
        }
    }
    __syncthreads();

    float best[8], sec[8]; int bidx[8];
#pragma unroll
    for (int s = 0; s < 8; ++s) { best[s] = -INFINITY; sec[s] = -INFINITY; bidx[s] = 0; }

#pragma unroll 1
    for (int nt = 0; nt < 4; ++nt) {
        const int n0 = nt * 256 + ng * 64;
        const int r16_0 = n0 >> 4;
        f4 acc[2][4];
#pragma unroll
        for (int mf = 0; mf < 2; ++mf)
#pragma unroll
            for (int nf = 0; nf < 4; ++nf) acc[mf][nf] = (f4)0.f;

#pragma unroll 2
        for (int kc = 0; kc < 8; ++kc) {
            h8 ah[2], al[2], bh[4];
#pragma unroll
            for (int mf = 0; mf < 2; ++mf) {
                const int ao = (((mh * 2 + mf) * 8 + kc) * 64 + l) * 16;
                ah[mf] = *(const h8*)(smem + ao);
                al[mf] = *(const h8*)(smem + 32768 + ao);
            }
#pragma unroll
            for (int nf = 0; nf < 4; ++nf) {
                const size_t bo = (((size_t)(r16_0 + nf) * 8 + kc) * 64 + l) * 8;
                bh[nf] = *(const h8*)(whS + bo);
            }
#pragma unroll
            for (int mf = 0; mf < 2; ++mf)
#pragma unroll
                for (int nf = 0; nf < 4; ++nf) {
                    acc[mf][nf] = __builtin_amdgcn_mfma_f32_16x16x32_f16(ah[mf], bh[nf], acc[mf][nf], 0, 0, 0);
                    acc[mf][nf] = __builtin_amdgcn_mfma_f32_16x16x32_f16(al[mf], bh[nf], acc[mf][nf], 0, 0, 0);
                }
        }
#pragma unroll
        for (int nf = 0; nf < 4; ++nf) {
            const int n_abs = n0 + nf * 16 + c15;
            const float bv = bias[n_abs];
#pragma unroll
            for (int mf = 0; mf < 2; ++mf)
#pragma unroll
                for (int r = 0; r < 4; ++r) {
                    const float v = acc[mf][nf][r] + bv;
                    const int s = mf * 4 + r;
                    if (v > best[s]) { sec[s] = best[s]; best[s] = v; bidx[s] = n_abs; }
                    else if (v > sec[s]) sec[s] = v;
                }
        }
    }

#pragma unroll
    for (int d = 1; d < 16; d <<= 1) {
#pragma unroll
        for (int s = 0; s < 8; ++s) {
            const float ob = __shfl_xor(best[s], d, 64);
            const float os = __shfl_xor(sec[s], d, 64);
            const int   oi = __shfl_xor(bidx[s], d, 64);
            if (ob > best[s])       { sec[s] = fmaxf(best[s], os); best[s] = ob; bidx[s] = oi; }
            else if (ob == best[s]) { sec[s] = ob; bidx[s] = (oi < bidx[s]) ? oi : bidx[s]; }
            else                    { sec[s] = fmaxf(sec[s], ob); }
        }
    }
#pragma unroll
    for (int s = 0; s < 8; ++s) {
        if (c15 == s) {
            const int px = (mh * 2 + (s >> 2)) * 16 + g * 4 + (s & 3);
            s_best[wv * 64 + px] = best[s];
            s_sec [wv * 64 + px] = sec[s];
            s_idx [wv * 64 + px] = bidx[s];
        }
    }
    __syncthreads();
    if (tid < 64) {
        const int wb = (tid >> 5) * 4;
        float b0 = s_best[wb * 64 + tid], s0 = s_sec[wb * 64 + tid]; int i0 = s_idx[wb * 64 + tid];
#pragma unroll
        for (int c = 1; c < 4; ++c) {
            const float ob = s_best[(wb + c) * 64 + tid], os = s_sec[(wb + c) * 64 + tid];
            const int   oi = s_idx [(wb + c) * 64 + tid];
            if (ob > b0 || (ob == b0 && oi < i0)) { s0 = fmaxf(b0, os); b0 = ob; i0 = oi; }
            else                                  { s0 = fmaxf(s0, ob); }
        }
        const int pix = pix0 + tid;
        indsh2[tid] = i0;
        out[ZQ_SIZE + 1 + pix] = (float)i0;
        if (b0 - s0 < MARGIN) {
            const int pos = atomicAdd(wcount, 1);
            if (pos < WLCAP) wlist[pos] = pix;
        }
    }
    if (blockIdx.x == 0 && tid == 0) out[ZQ_SIZE] = 0.0f;
    __syncthreads();

    float (*tile)[257] = (float (*)[257])smem;
    const int lq = tid & 63, wq = tid >> 6;
    const int l32 = tid & 31, dq = tid >> 5;
#pragma unroll 1
    for (int pp = 0; pp < 2; ++pp) {
#pragma unroll
        for (int it = 0; it < 4; ++it) {
            const int pl = it * 8 + wq;
            const int row = indsh2[pp * 32 + pl];
            const float4 e = *(const float4*)(embed + (size_t)row * DD + lq * 4);
            tile[pl][lq * 4 + 0] = e.x;
            tile[pl][lq * 4 + 1] = e.y;
            tile[pl][lq * 4 + 2] = e.z;
            tile[pl][lq * 4 + 3] = e.w;
        }
        __syncthreads();
        float* outz = out + (size_t)b * DD * HWP + p0 + pp * 32;
#pragma unroll
        for (int dd = 0; dd < 16; ++dd) {
            const int d = dd * 16 + dq;
            outz[(size_t)d * HWP + l32] = tile[l32][d];
        }
        __syncthreads();
    }
}

// ---------- K3: exact-fp32 fixup — 8 px/group, 8 waves x 128 rows ----------
// R8 structure (z once per group, rows across waves, batched w loads) was
// right; it SPILLED (w4[16]=64 regs + part[8]+... > 128 cap -> 360 MB scratch
// = the 428 us). Fix: batch of 8 float4 (32 regs, demand ~80) + explicit
// __launch_bounds__(512,2) cap 128. Two ~300cyc waits per g16 instead of 16
// chained loads (R6's 59 us chain) or one spilled batch of 16 (R8).
__global__ __launch_bounds__(512, 2) void fixup_k(
    const float* __restrict__ z, const float* __restrict__ w,
    const float* __restrict__ bias, const float* __restrict__ embed,
    const int* __restrict__ wcount, const int* __restrict__ wlist,
    float* __restrict__ out)
{
    __shared__ float zsh[PXB][256];
    __shared__ float m_v[8][PXB];
    __shared__ int   m_i[8][PXB];
    __shared__ int   s_idx[PXB];

    const int tid = threadIdx.x;
    const int l = tid & 63, wv = tid >> 6;      // 8 waves
    const int c15 = l & 15, q = l >> 4;
    int nw = *wcount;
    if (nw > WLCAP) nw = WLCAP;
    if (nw < 0) nw = 0;
    const int npg = (nw + PXB - 1) / PXB;

    for (int pg = blockIdx.x; pg < npg; pg += 512) {
        const int e0 = pg * PXB;
        const int npx = (nw - e0 < PXB) ? (nw - e0) : PXB;
        int pixv[PXB];
#pragma unroll
        for (int px = 0; px < PXB; ++px)
            pixv[px] = wlist[e0 + ((px < npx) ? px : (npx - 1))];

        __syncthreads();   // guard zsh/s_idx reuse across pg-iterations
        // z gather ONCE: 2048 scattered loads spread over 512 threads
#pragma unroll
        for (int it = 0; it < (PXB * 256) / 512; ++it) {
            const int i = it * 512 + tid;
            const int px = i >> 8, c = i & 255;
            const int pix = pixv[px];
            const int b = pix >> 12, p = pix & 4095;
            zsh[px][c] = z[((size_t)b * CCH + c) * HWP + p];
        }
        __syncthreads();

        float best[PXB]; int bi[PXB];
#pragma unroll
        for (int px = 0; px < PXB; ++px) { best[px] = -INFINITY; bi[px] = 0; }

#pragma unroll 1
        for (int g16 = 0; g16 < 8; ++g16) {
            const int row = wv * 128 + g16 * 16 + c15;
            const float* wr = w + (size_t)row * CCH + q * 64;
            float part[PXB];
#pragma unroll
            for (int px = 0; px < PXB; ++px) part[px] = 0.f;
            // two half-batches of 8 float4 (32 regs live, not 64 -> no spill)
#pragma unroll
            for (int h = 0; h < 2; ++h) {
                float4 w4[8];
#pragma unroll
                for (int j = 0; j < 8; ++j) w4[j] = *(const float4*)(wr + h * 32 + j * 4);
#pragma unroll
                for (int j = 0; j < 8; ++j) {
#pragma unroll
                    for (int px = 0; px < PXB; ++px) {
                        const float4 z4 = *(const float4*)&zsh[px][q * 64 + h * 32 + j * 4];
                        part[px] = fmaf(w4[j].x, z4.x, part[px]);
                        part[px] = fmaf(w4[j].y, z4.y, part[px]);
                        part[px] = fmaf(w4[j].z, z4.z, part[px]);
                        part[px] = fmaf(w4[j].w, z4.w, part[px]);
                    }
                }
            }
            const float bv = bias[row];
#pragma unroll
            for (int px = 0; px < PXB; ++px) {
                float pv = part[px];
                pv += __shfl_xor(pv, 16, 64);
                pv += __shfl_xor(pv, 32, 64);
                const float v = pv + bv;
                if (v > best[px]) { best[px] = v; bi[px] = row; }   // row ascends -> min idx kept
            }
        }
        // butterfly over the 16 col-lanes
#pragma unroll
        for (int d = 1; d < 16; d <<= 1) {
#pragma unroll
            for (int px = 0; px < PXB; ++px) {
                const float ob = __shfl_xor(best[px], d, 64);
                const int   oi = __shfl_xor(bi[px], d, 64);
                if (ob > best[px] || (ob == best[px] && oi < bi[px])) { best[px] = ob; bi[px] = oi; }
            }
        }
        if (l == 0) {
#pragma unroll
            for (int px = 0; px < PXB; ++px) { m_v[wv][px] = best[px]; m_i[wv][px] = bi[px]; }
        }
        __syncthreads();
        if (tid < npx) {
            float v = m_v[0][tid]; int i = m_i[0][tid];
#pragma unroll
            for (int w2 = 1; w2 < 8; ++w2)
                if (m_v[w2][tid] > v || (m_v[w2][tid] == v && m_i[w2][tid] < i)) { v = m_v[w2][tid]; i = m_i[w2][tid]; }
            s_idx[tid] = i;
            out[ZQ_SIZE + 1 + pixv[tid]] = (float)i;
        }
        __syncthreads();
        // z_q rewrite: 2 px per pass across 512 threads
#pragma unroll
        for (int pp = 0; pp < PXB; pp += 2) {
            const int px = pp + (tid >> 8);
            const int d = tid & 255;
            if (px < npx) {
                const int pix = pixv[px];
                const int b = pix >> 12, p = pix & 4095;
                out[((size_t)b * DD + d) * HWP + p] = embed[(size_t)s_idx[px] * DD + d];
            }
        }
    }
}

extern "C" void kernel_launch(void* const* d_in, const int* in_sizes, int n_in,
                              void* d_out, int out_size, void* d_ws, size_t ws_size,
                              hipStream_t stream) {
    const float* z     = (const float*)d_in[0];
    const float* w     = (const float*)d_in[1];
    const float* bias  = (const float*)d_in[2];
    const float* embed = (const float*)d_in[3];
    float* out = (float*)d_out;

    // ws: whS 512K | wcount | wlist 16K
    _Float16* whS = (_Float16*)d_ws;
    int* wcount = (int*)((char*)d_ws + 524288);
    int* wlist  = (int*)((char*)d_ws + 524544);

    hipLaunchKernelGGL(split_w_k,   dim3(128), dim3(256), 0, stream, w, whS, wcount);
    hipLaunchKernelGGL(mfma_gemm_k, dim3(512), dim3(512), 0, stream,
                       z, whS, bias, embed, wcount, wlist, out);
    hipLaunchKernelGGL(fixup_k,     dim3(512), dim3(512), 0, stream,
                       z, w, bias, embed, wcount, wlist, out);
}

// Round 10
// 241.010 us; speedup vs baseline: 2.2990x; 1.4452x over previous
//
#include <hip/hip_runtime.h>
#include <math.h>

#define HWP 4096
#define CCH 256
#define NN  1024
#define DD  256
#define ZQ_SIZE (8 * DD * HWP)       // 8388608 floats
#define MARGIN 2e-3f                 // 2-product screening: gap-err std 1.3e-4 -> 15 sigma
#define WLCAP 4096
#define PXB 8                        // fixup pixels per group

typedef _Float16 h8 __attribute__((ext_vector_type(8)));
typedef float    f4 __attribute__((ext_vector_type(4)));

// ---------- K1: w -> fp16 (hi only), SWIZZLED fragment order ----------
// whS: [r16 0..63][kc 0..7][lane 0..63][j 0..7] halfs.
__global__ __launch_bounds__(256) void split_w_k(
    const float* __restrict__ w, _Float16* __restrict__ whS,
    int* __restrict__ wcount)
{
    if (blockIdx.x == 0 && threadIdx.x == 0) *wcount = 0;
    const int t = blockIdx.x * 256 + threadIdx.x;
    const int l = t & 63;
    const int frag = t >> 6;
    const int kc = frag & 7, r16 = frag >> 3;
    const int row = r16 * 16 + (l & 15);
    const int c   = kc * 32 + (l >> 4) * 8;
    const float* src = w + (size_t)row * CCH + c;
    _Float16 hv[8];
#pragma unroll
    for (int j = 0; j < 8; ++j) hv[j] = (_Float16)src[j];
    *(h8*)(whS + (size_t)t * 8) = *(const h8*)hv;
}

// ---------- K2: fused z-split + 2-product MFMA GEMM + top2 + gather ----------
// VERBATIM R6 (proven 62.2 us, VGPR 56, spill-free, absmax 0).
__global__ __launch_bounds__(512, 4) void mfma_gemm_k(
    const float* __restrict__ z,
    const _Float16* __restrict__ whS,
    const float* __restrict__ bias, const float* __restrict__ embed,
    int* __restrict__ wcount, int* __restrict__ wlist,
    float* __restrict__ out)
{
    __shared__ __align__(16) char smem[71680];
    __shared__ int indsh2[64];
    float* s_best = (float*)(smem + 65536);     // [8][64]
    float* s_sec  = (float*)(smem + 67584);
    int*   s_idx  = (int*)  (smem + 69632);

    const int tid = threadIdx.x;
    const int l   = tid & 63;
    const int wv  = tid >> 6;                   // 0..7
    const int mh  = wv >> 2;                    // pixel half: px in [32*mh, 32*mh+32)
    const int ng  = wv & 3;                     // n-group
    const int c15 = l & 15, g = l >> 4;
    const int pix0 = blockIdx.x * 64;
    const int b = pix0 >> 12, p0 = pix0 & 4095;

    // ---- Stage A: z -> hi/lo fp16 frag-order LDS ----
    {
        const int px = tid & 63;
        const int wv2 = tid >> 6;                // 0..7
        const int p16 = px >> 4;
        const float* zb = z + (size_t)b * CCH * HWP + p0 + px;
#pragma unroll
        for (int it = 0; it < 4; ++it) {
            const int cg = wv2 * 4 + it;         // c-group of 8 (0..31)
            const int c = cg * 8;
            float xv[8];
#pragma unroll
            for (int i = 0; i < 8; ++i) xv[i] = zb[(size_t)(c + i) * HWP];
            _Float16 hv[8], lv[8];
#pragma unroll
            for (int i = 0; i < 8; ++i) {
                const _Float16 h = (_Float16)xv[i];
                hv[i] = h;
                lv[i] = (_Float16)(xv[i] - (float)h);
            }
            const int kc = cg >> 2;
            const int lane = (px & 15) + 16 * (cg & 3);
            const int off = ((p16 * 8 + kc) * 64 + lane) * 16;   // bytes, < 32768
            *(h8*)(smem + off)         = *(const h8*)hv;
            *(h8*)(smem + 32768 + off) = *(const h8*)lv;
        }
    }
    __syncthreads();

    float best[8], sec[8]; int bidx[8];
#pragma unroll
    for (int s = 0; s < 8; ++s) { best[s] = -INFINITY; sec[s] = -INFINITY; bidx[s] = 0; }

#pragma unroll 1
    for (int nt = 0; nt < 4; ++nt) {
        const int n0 = nt * 256 + ng * 64;
        const int r16_0 = n0 >> 4;
        f4 acc[2][4];
#pragma unroll
        for (int mf = 0; mf < 2; ++mf)
#pragma unroll
            for (int nf = 0; nf < 4; ++nf) acc[mf][nf] = (f4)0.f;

#pragma unroll 2
        for (int kc = 0; kc < 8; ++kc) {
            h8 ah[2], al[2], bh[4];
#pragma unroll
            for (int mf = 0; mf < 2; ++mf) {
                const int ao = (((mh * 2 + mf) * 8 + kc) * 64 + l) * 16;
                ah[mf] = *(const h8*)(smem + ao);
                al[mf] = *(const h8*)(smem + 32768 + ao);
            }
#pragma unroll
            for (int nf = 0; nf < 4; ++nf) {
                const size_t bo = (((size_t)(r16_0 + nf) * 8 + kc) * 64 + l) * 8;
                bh[nf] = *(const h8*)(whS + bo);
            }
#pragma unroll
            for (int mf = 0; mf < 2; ++mf)
#pragma unroll
                for (int nf = 0; nf < 4; ++nf) {
                    acc[mf][nf] = __builtin_amdgcn_mfma_f32_16x16x32_f16(ah[mf], bh[nf], acc[mf][nf], 0, 0, 0);
                    acc[mf][nf] = __builtin_amdgcn_mfma_f32_16x16x32_f16(al[mf], bh[nf], acc[mf][nf], 0, 0, 0);
                }
        }
#pragma unroll
        for (int nf = 0; nf < 4; ++nf) {
            const int n_abs = n0 + nf * 16 + c15;
            const float bv = bias[n_abs];
#pragma unroll
            for (int mf = 0; mf < 2; ++mf)
#pragma unroll
                for (int r = 0; r < 4; ++r) {
                    const float v = acc[mf][nf][r] + bv;
                    const int s = mf * 4 + r;
                    if (v > best[s]) { sec[s] = best[s]; best[s] = v; bidx[s] = n_abs; }
                    else if (v > sec[s]) sec[s] = v;
                }
        }
    }

#pragma unroll
    for (int d = 1; d < 16; d <<= 1) {
#pragma unroll
        for (int s = 0; s < 8; ++s) {
            const float ob = __shfl_xor(best[s], d, 64);
            const float os = __shfl_xor(sec[s], d, 64);
            const int   oi = __shfl_xor(bidx[s], d, 64);
            if (ob > best[s])       { sec[s] = fmaxf(best[s], os); best[s] = ob; bidx[s] = oi; }
            else if (ob == best[s]) { sec[s] = ob; bidx[s] = (oi < bidx[s]) ? oi : bidx[s]; }
            else                    { sec[s] = fmaxf(sec[s], ob); }
        }
    }
#pragma unroll
    for (int s = 0; s < 8; ++s) {
        if (c15 == s) {
            const int px = (mh * 2 + (s >> 2)) * 16 + g * 4 + (s & 3);
            s_best[wv * 64 + px] = best[s];
            s_sec [wv * 64 + px] = sec[s];
            s_idx [wv * 64 + px] = bidx[s];
        }
    }
    __syncthreads();
    if (tid < 64) {
        const int wb = (tid >> 5) * 4;
        float b0 = s_best[wb * 64 + tid], s0 = s_sec[wb * 64 + tid]; int i0 = s_idx[wb * 64 + tid];
#pragma unroll
        for (int c = 1; c < 4; ++c) {
            const float ob = s_best[(wb + c) * 64 + tid], os = s_sec[(wb + c) * 64 + tid];
            const int   oi = s_idx [(wb + c) * 64 + tid];
            if (ob > b0 || (ob == b0 && oi < i0)) { s0 = fmaxf(b0, os); b0 = ob; i0 = oi; }
            else                                  { s0 = fmaxf(s0, ob); }
        }
        const int pix = pix0 + tid;
        indsh2[tid] = i0;
        out[ZQ_SIZE + 1 + pix] = (float)i0;
        if (b0 - s0 < MARGIN) {
            const int pos = atomicAdd(wcount, 1);
            if (pos < WLCAP) wlist[pos] = pix;
        }
    }
    if (blockIdx.x == 0 && tid == 0) out[ZQ_SIZE] = 0.0f;
    __syncthreads();

    float (*tile)[257] = (float (*)[257])smem;
    const int lq = tid & 63, wq = tid >> 6;
    const int l32 = tid & 31, dq = tid >> 5;
#pragma unroll 1
    for (int pp = 0; pp < 2; ++pp) {
#pragma unroll
        for (int it = 0; it < 4; ++it) {
            const int pl = it * 8 + wq;
            const int row = indsh2[pp * 32 + pl];
            const float4 e = *(const float4*)(embed + (size_t)row * DD + lq * 4);
            tile[pl][lq * 4 + 0] = e.x;
            tile[pl][lq * 4 + 1] = e.y;
            tile[pl][lq * 4 + 2] = e.z;
            tile[pl][lq * 4 + 3] = e.w;
        }
        __syncthreads();
        float* outz = out + (size_t)b * DD * HWP + p0 + pp * 32;
#pragma unroll
        for (int dd = 0; dd < 16; ++dd) {
            const int d = dd * 16 + dq;
            outz[(size_t)d * HWP + l32] = tile[l32][d];
        }
        __syncthreads();
    }
}

// ---------- K3: exact-fp32 fixup — R6 shape (256 thr, VGPR headroom) + batched loads ----------
// Evidence-complete diagnosis:
//   R6 (256 thr, VGPR 160, no spill): loads issued inside j-loop -> 16 serial
//     ~500cyc waits per g16 -> 59 us.
//   R8/R9 (512 thr): hoisted batch correct, but 512-thr caps VGPR at 128 ->
//     spill -> 360/255 MB scratch -> 428/223 us.
// Fix: 256 threads (cap 256 VGPR), 4 waves x 16 g16, hoisted w4[16] batch
// (demand ~125 regs, provably under cap). z gathered ONCE per 8-px group
// (R7 lesson). Self-contained blocks, no atomics. Per g16: one batched wait
// + 512 FMA -> ~22K cyc/block, ~100 parallel blocks -> ~10 us.
__global__ __launch_bounds__(256) void fixup_k(
    const float* __restrict__ z, const float* __restrict__ w,
    const float* __restrict__ bias, const float* __restrict__ embed,
    const int* __restrict__ wcount, const int* __restrict__ wlist,
    float* __restrict__ out)
{
    __shared__ float zsh[PXB][256];
    __shared__ float m_v[4][PXB];
    __shared__ int   m_i[4][PXB];
    __shared__ int   s_idx[PXB];

    const int tid = threadIdx.x;
    const int l = tid & 63, wv = tid >> 6;      // 4 waves
    const int c15 = l & 15, q = l >> 4;
    int nw = *wcount;
    if (nw > WLCAP) nw = WLCAP;
    if (nw < 0) nw = 0;
    const int npg = (nw + PXB - 1) / PXB;

    for (int pg = blockIdx.x; pg < npg; pg += 512) {
        const int e0 = pg * PXB;
        const int npx = (nw - e0 < PXB) ? (nw - e0) : PXB;
        int pixv[PXB];
#pragma unroll
        for (int px = 0; px < PXB; ++px)
            pixv[px] = wlist[e0 + ((px < npx) ? px : (npx - 1))];

        __syncthreads();   // guard zsh/s_idx reuse across pg-iterations
        // z gather ONCE: 2048 scattered loads over 256 threads (independent -> one wait)
#pragma unroll
        for (int it = 0; it < (PXB * 256) / 256; ++it) {
            const int i = it * 256 + tid;
            const int px = i >> 8, c = i & 255;
            const int pix = pixv[px];
            const int b = pix >> 12, p = pix & 4095;
            zsh[px][c] = z[((size_t)b * CCH + c) * HWP + p];
        }
        __syncthreads();

        float best[PXB]; int bi[PXB];
#pragma unroll
        for (int px = 0; px < PXB; ++px) { best[px] = -INFINITY; bi[px] = 0; }

#pragma unroll 1
        for (int g16 = 0; g16 < 16; ++g16) {
            const int row = wv * 256 + g16 * 16 + c15;
            const float* wr = w + (size_t)row * CCH + q * 64;
            // hoisted batch: all 16 w-float4 issued before any use (one wait)
            float4 w4[16];
#pragma unroll
            for (int j = 0; j < 16; ++j) w4[j] = *(const float4*)(wr + j * 4);
            float part[PXB];
#pragma unroll
            for (int px = 0; px < PXB; ++px) part[px] = 0.f;
#pragma unroll
            for (int j = 0; j < 16; ++j) {
#pragma unroll
                for (int px = 0; px < PXB; ++px) {
                    const float4 z4 = *(const float4*)&zsh[px][q * 64 + j * 4];
                    part[px] = fmaf(w4[j].x, z4.x, part[px]);
                    part[px] = fmaf(w4[j].y, z4.y, part[px]);
                    part[px] = fmaf(w4[j].z, z4.z, part[px]);
                    part[px] = fmaf(w4[j].w, z4.w, part[px]);
                }
            }
            const float bv = bias[row];
#pragma unroll
            for (int px = 0; px < PXB; ++px) {
                float pv = part[px];
                pv += __shfl_xor(pv, 16, 64);
                pv += __shfl_xor(pv, 32, 64);
                const float v = pv + bv;
                if (v > best[px]) { best[px] = v; bi[px] = row; }   // row ascends -> min idx kept
            }
        }
        // butterfly over the 16 col-lanes
#pragma unroll
        for (int d = 1; d < 16; d <<= 1) {
#pragma unroll
            for (int px = 0; px < PXB; ++px) {
                const float ob = __shfl_xor(best[px], d, 64);
                const int   oi = __shfl_xor(bi[px], d, 64);
                if (ob > best[px] || (ob == best[px] && oi < bi[px])) { best[px] = ob; bi[px] = oi; }
            }
        }
        if (l == 0) {
#pragma unroll
            for (int px = 0; px < PXB; ++px) { m_v[wv][px] = best[px]; m_i[wv][px] = bi[px]; }
        }
        __syncthreads();
        if (tid < npx) {
            float v = m_v[0][tid]; int i = m_i[0][tid];
#pragma unroll
            for (int w2 = 1; w2 < 4; ++w2)
                if (m_v[w2][tid] > v || (m_v[w2][tid] == v && m_i[w2][tid] < i)) { v = m_v[w2][tid]; i = m_i[w2][tid]; }
            s_idx[tid] = i;
            out[ZQ_SIZE + 1 + pixv[tid]] = (float)i;
        }
        __syncthreads();
        // z_q rewrite: 256 threads = 256 d-channels, one px at a time
        for (int px = 0; px < npx; ++px) {
            const int pix = pixv[px];
            const int b = pix >> 12, p = pix & 4095;
            out[((size_t)b * DD + tid) * HWP + p] = embed[(size_t)s_idx[px] * DD + tid];
        }
    }
}

extern "C" void kernel_launch(void* const* d_in, const int* in_sizes, int n_in,
                              void* d_out, int out_size, void* d_ws, size_t ws_size,
                              hipStream_t stream) {
    const float* z     = (const float*)d_in[0];
    const float* w     = (const float*)d_in[1];
    const float* bias  = (const float*)d_in[2];
    const float* embed = (const float*)d_in[3];
    float* out = (float*)d_out;

    // ws: whS 512K | wcount | wlist 16K
    _Float16* whS = (_Float16*)d_ws;
    int* wcount = (int*)((char*)d_ws + 524288);
    int* wlist  = (int*)((char*)d_ws + 524544);

    hipLaunchKernelGGL(split_w_k,   dim3(128), dim3(256), 0, stream, w, whS, wcount);
    hipLaunchKernelGGL(mfma_gemm_k, dim3(512), dim3(512), 0, stream,
                       z, whS, bias, embed, wcount, wlist, out);
    hipLaunchKernelGGL(fixup_k,     dim3(512), dim3(256), 0, stream,
                       z, w, bias, embed, wcount, wlist, out);
}

// Round 11
// 195.574 us; speedup vs baseline: 2.8332x; 1.2323x over previous
//
#include <hip/hip_runtime.h>
#include <math.h>

#define HWP 4096
#define CCH 256
#define NN  1024
#define DD  256
#define ZQ_SIZE (8 * DD * HWP)       // 8388608 floats
#define MARGIN 2e-3f                 // 2-product screening: gap-err std 1.3e-4 -> 15 sigma
#define WLCAP 4096
#define PXB 2                        // fixup pixels per group (R11: 8->2 for grid parallelism)

typedef _Float16 h8 __attribute__((ext_vector_type(8)));
typedef float    f4 __attribute__((ext_vector_type(4)));

// ---------- K1: w -> fp16 (hi only), SWIZZLED fragment order ----------
// whS: [r16 0..63][kc 0..7][lane 0..63][j 0..7] halfs.
__global__ __launch_bounds__(256) void split_w_k(
    const float* __restrict__ w, _Float16* __restrict__ whS,
    int* __restrict__ wcount)
{
    if (blockIdx.x == 0 && threadIdx.x == 0) *wcount = 0;
    const int t = blockIdx.x * 256 + threadIdx.x;
    const int l = t & 63;
    const int frag = t >> 6;
    const int kc = frag & 7, r16 = frag >> 3;
    const int row = r16 * 16 + (l & 15);
    const int c   = kc * 32 + (l >> 4) * 8;
    const float* src = w + (size_t)row * CCH + c;
    _Float16 hv[8];
#pragma unroll
    for (int j = 0; j < 8; ++j) hv[j] = (_Float16)src[j];
    *(h8*)(whS + (size_t)t * 8) = *(const h8*)hv;
}

// ---------- K2: fused z-split + 2-product MFMA GEMM + top2 + gather ----------
// VERBATIM R6 (proven 62.2 us, VGPR 56, spill-free, absmax 0).
__global__ __launch_bounds__(512, 4) void mfma_gemm_k(
    const float* __restrict__ z,
    const _Float16* __restrict__ whS,
    const float* __restrict__ bias, const float* __restrict__ embed,
    int* __restrict__ wcount, int* __restrict__ wlist,
    float* __restrict__ out)
{
    __shared__ __align__(16) char smem[71680];
    __shared__ int indsh2[64];
    float* s_best = (float*)(smem + 65536);     // [8][64]
    float* s_sec  = (float*)(smem + 67584);
    int*   s_idx  = (int*)  (smem + 69632);

    const int tid = threadIdx.x;
    const int l   = tid & 63;
    const int wv  = tid >> 6;                   // 0..7
    const int mh  = wv >> 2;                    // pixel half: px in [32*mh, 32*mh+32)
    const int ng  = wv & 3;                     // n-group
    const int c15 = l & 15, g = l >> 4;
    const int pix0 = blockIdx.x * 64;
    const int b = pix0 >> 12, p0 = pix0 & 4095;

    // ---- Stage A: z -> hi/lo fp16 frag-order LDS ----
    {
        const int px = tid & 63;
        const int wv2 = tid >> 6;                // 0..7
        const int p16 = px >> 4;
        const float* zb = z + (size_t)b * CCH * HWP + p0 + px;
#pragma unroll
        for (int it = 0; it < 4; ++it) {
            const int cg = wv2 * 4 + it;         // c-group of 8 (0..31)
            const int c = cg * 8;
            float xv[8];
#pragma unroll
            for (int i = 0; i < 8; ++i) xv[i] = zb[(size_t)(c + i) * HWP];
            _Float16 hv[8], lv[8];
#pragma unroll
            for (int i = 0; i < 8; ++i) {
                const _Float16 h = (_Float16)xv[i];
                hv[i] = h;
                lv[i] = (_Float16)(xv[i] - (float)h);
            }
            const int kc = cg >> 2;
            const int lane = (px & 15) + 16 * (cg & 3);
            const int off = ((p16 * 8 + kc) * 64 + lane) * 16;   // bytes, < 32768
            *(h8*)(smem + off)         = *(const h8*)hv;
            *(h8*)(smem + 32768 + off) = *(const h8*)lv;
        }
    }
    __syncthreads();

    float best[8], sec[8]; int bidx[8];
#pragma unroll
    for (int s = 0; s < 8; ++s) { best[s] = -INFINITY; sec[s] = -INFINITY; bidx[s] = 0; }

#pragma unroll 1
    for (int nt = 0; nt < 4; ++nt) {
        const int n0 = nt * 256 + ng * 64;
        const int r16_0 = n0 >> 4;
        f4 acc[2][4];
#pragma unroll
        for (int mf = 0; mf < 2; ++mf)
#pragma unroll
            for (int nf = 0; nf < 4; ++nf) acc[mf][nf] = (f4)0.f;

#pragma unroll 2
        for (int kc = 0; kc < 8; ++kc) {
            h8 ah[2], al[2], bh[4];
#pragma unroll
            for (int mf = 0; mf < 2; ++mf) {
                const int ao = (((mh * 2 + mf) * 8 + kc) * 64 + l) * 16;
                ah[mf] = *(const h8*)(smem + ao);
                al[mf] = *(const h8*)(smem + 32768 + ao);
            }
#pragma unroll
            for (int nf = 0; nf < 4; ++nf) {
                const size_t bo = (((size_t)(r16_0 + nf) * 8 + kc) * 64 + l) * 8;
                bh[nf] = *(const h8*)(whS + bo);
            }
#pragma unroll
            for (int mf = 0; mf < 2; ++mf)
#pragma unroll
                for (int nf = 0; nf < 4; ++nf) {
                    acc[mf][nf] = __builtin_amdgcn_mfma_f32_16x16x32_f16(ah[mf], bh[nf], acc[mf][nf], 0, 0, 0);
                    acc[mf][nf] = __builtin_amdgcn_mfma_f32_16x16x32_f16(al[mf], bh[nf], acc[mf][nf], 0, 0, 0);
                }
        }
#pragma unroll
        for (int nf = 0; nf < 4; ++nf) {
            const int n_abs = n0 + nf * 16 + c15;
            const float bv = bias[n_abs];
#pragma unroll
            for (int mf = 0; mf < 2; ++mf)
#pragma unroll
                for (int r = 0; r < 4; ++r) {
                    const float v = acc[mf][nf][r] + bv;
                    const int s = mf * 4 + r;
                    if (v > best[s]) { sec[s] = best[s]; best[s] = v; bidx[s] = n_abs; }
                    else if (v > sec[s]) sec[s] = v;
                }
        }
    }

#pragma unroll
    for (int d = 1; d < 16; d <<= 1) {
#pragma unroll
        for (int s = 0; s < 8; ++s) {
            const float ob = __shfl_xor(best[s], d, 64);
            const float os = __shfl_xor(sec[s], d, 64);
            const int   oi = __shfl_xor(bidx[s], d, 64);
            if (ob > best[s])       { sec[s] = fmaxf(best[s], os); best[s] = ob; bidx[s] = oi; }
            else if (ob == best[s]) { sec[s] = ob; bidx[s] = (oi < bidx[s]) ? oi : bidx[s]; }
            else                    { sec[s] = fmaxf(sec[s], ob); }
        }
    }
#pragma unroll
    for (int s = 0; s < 8; ++s) {
        if (c15 == s) {
            const int px = (mh * 2 + (s >> 2)) * 16 + g * 4 + (s & 3);
            s_best[wv * 64 + px] = best[s];
            s_sec [wv * 64 + px] = sec[s];
            s_idx [wv * 64 + px] = bidx[s];
        }
    }
    __syncthreads();
    if (tid < 64) {
        const int wb = (tid >> 5) * 4;
        float b0 = s_best[wb * 64 + tid], s0 = s_sec[wb * 64 + tid]; int i0 = s_idx[wb * 64 + tid];
#pragma unroll
        for (int c = 1; c < 4; ++c) {
            const float ob = s_best[(wb + c) * 64 + tid], os = s_sec[(wb + c) * 64 + tid];
            const int   oi = s_idx [(wb + c) * 64 + tid];
            if (ob > b0 || (ob == b0 && oi < i0)) { s0 = fmaxf(b0, os); b0 = ob; i0 = oi; }
            else                                  { s0 = fmaxf(s0, ob); }
        }
        const int pix = pix0 + tid;
        indsh2[tid] = i0;
        out[ZQ_SIZE + 1 + pix] = (float)i0;
        if (b0 - s0 < MARGIN) {
            const int pos = atomicAdd(wcount, 1);
            if (pos < WLCAP) wlist[pos] = pix;
        }
    }
    if (blockIdx.x == 0 && tid == 0) out[ZQ_SIZE] = 0.0f;
    __syncthreads();

    float (*tile)[257] = (float (*)[257])smem;
    const int lq = tid & 63, wq = tid >> 6;
    const int l32 = tid & 31, dq = tid >> 5;
#pragma unroll 1
    for (int pp = 0; pp < 2; ++pp) {
#pragma unroll
        for (int it = 0; it < 4; ++it) {
            const int pl = it * 8 + wq;
            const int row = indsh2[pp * 32 + pl];
            const float4 e = *(const float4*)(embed + (size_t)row * DD + lq * 4);
            tile[pl][lq * 4 + 0] = e.x;
            tile[pl][lq * 4 + 1] = e.y;
            tile[pl][lq * 4 + 2] = e.z;
            tile[pl][lq * 4 + 3] = e.w;
        }
        __syncthreads();
        float* outz = out + (size_t)b * DD * HWP + p0 + pp * 32;
#pragma unroll
        for (int dd = 0; dd < 16; ++dd) {
            const int d = dd * 16 + dq;
            outz[(size_t)d * HWP + l32] = tile[l32][d];
        }
        __syncthreads();
    }
}

// ---------- K3: exact-fp32 fixup — PXB=2, ~400 parallel blocks ----------
// R10 post-mortem: spill fixed (FETCH 16.7 MB) but npg~100 blocks -> 1 block/CU,
// 1 wave/SIMD -> per-block serial chain (16 g16 x ~7us of exposed ds->fma +
// w-wait latency) = the 124 us. Fix: PXB 8->2 -> npg~400 blocks (>=1.6/CU,
// waves overlap), per-g16 work 4x smaller (32 ds_read + 128 fma), register
// demand DOWN (~90 <= 256-thr cap; R9 rule). z still gathered once per pixel
// (R7 rule). Self-contained blocks, no atomics.
__global__ __launch_bounds__(256) void fixup_k(
    const float* __restrict__ z, const float* __restrict__ w,
    const float* __restrict__ bias, const float* __restrict__ embed,
    const int* __restrict__ wcount, const int* __restrict__ wlist,
    float* __restrict__ out)
{
    __shared__ float zsh[PXB][256];
    __shared__ float m_v[4][PXB];
    __shared__ int   m_i[4][PXB];
    __shared__ int   s_idx[PXB];

    const int tid = threadIdx.x;
    const int l = tid & 63, wv = tid >> 6;      // 4 waves
    const int c15 = l & 15, q = l >> 4;
    int nw = *wcount;
    if (nw > WLCAP) nw = WLCAP;
    if (nw < 0) nw = 0;
    const int npg = (nw + PXB - 1) / PXB;

    for (int pg = blockIdx.x; pg < npg; pg += 1024) {
        const int e0 = pg * PXB;
        const int npx = (nw - e0 < PXB) ? (nw - e0) : PXB;
        int pixv[PXB];
#pragma unroll
        for (int px = 0; px < PXB; ++px)
            pixv[px] = wlist[e0 + ((px < npx) ? px : (npx - 1))];

        __syncthreads();   // guard zsh/s_idx reuse across pg-iterations
        // z gather ONCE per pixel: 512 scattered loads over 256 threads
#pragma unroll
        for (int px = 0; px < PXB; ++px) {
            const int pix = pixv[px];
            const int b = pix >> 12, p = pix & 4095;
            zsh[px][tid] = z[((size_t)b * CCH + tid) * HWP + p];
        }
        __syncthreads();

        float best[PXB]; int bi[PXB];
#pragma unroll
        for (int px = 0; px < PXB; ++px) { best[px] = -INFINITY; bi[px] = 0; }

#pragma unroll 1
        for (int g16 = 0; g16 < 16; ++g16) {
            const int row = wv * 256 + g16 * 16 + c15;
            const float* wr = w + (size_t)row * CCH + q * 64;
            // hoisted batch: all 16 w-float4 issued before any use (one wait)
            float4 w4[16];
#pragma unroll
            for (int j = 0; j < 16; ++j) w4[j] = *(const float4*)(wr + j * 4);
            float part[PXB];
#pragma unroll
            for (int px = 0; px < PXB; ++px) part[px] = 0.f;
#pragma unroll
            for (int j = 0; j < 16; ++j) {
#pragma unroll
                for (int px = 0; px < PXB; ++px) {
                    const float4 z4 = *(const float4*)&zsh[px][q * 64 + j * 4];
                    part[px] = fmaf(w4[j].x, z4.x, part[px]);
                    part[px] = fmaf(w4[j].y, z4.y, part[px]);
                    part[px] = fmaf(w4[j].z, z4.z, part[px]);
                    part[px] = fmaf(w4[j].w, z4.w, part[px]);
                }
            }
            const float bv = bias[row];
#pragma unroll
            for (int px = 0; px < PXB; ++px) {
                float pv = part[px];
                pv += __shfl_xor(pv, 16, 64);
                pv += __shfl_xor(pv, 32, 64);
                const float v = pv + bv;
                if (v > best[px]) { best[px] = v; bi[px] = row; }   // row ascends -> min idx kept
            }
        }
        // butterfly over the 16 col-lanes
#pragma unroll
        for (int d = 1; d < 16; d <<= 1) {
#pragma unroll
            for (int px = 0; px < PXB; ++px) {
                const float ob = __shfl_xor(best[px], d, 64);
                const int   oi = __shfl_xor(bi[px], d, 64);
                if (ob > best[px] || (ob == best[px] && oi < bi[px])) { best[px] = ob; bi[px] = oi; }
            }
        }
        if (l == 0) {
#pragma unroll
            for (int px = 0; px < PXB; ++px) { m_v[wv][px] = best[px]; m_i[wv][px] = bi[px]; }
        }
        __syncthreads();
        if (tid < npx) {
            float v = m_v[0][tid]; int i = m_i[0][tid];
#pragma unroll
            for (int w2 = 1; w2 < 4; ++w2)
                if (m_v[w2][tid] > v || (m_v[w2][tid] == v && m_i[w2][tid] < i)) { v = m_v[w2][tid]; i = m_i[w2][tid]; }
            s_idx[tid] = i;
            out[ZQ_SIZE + 1 + pixv[tid]] = (float)i;
        }
        __syncthreads();
        // z_q rewrite: 256 threads = 256 d-channels, one px at a time
        for (int px = 0; px < npx; ++px) {
            const int pix = pixv[px];
            const int b = pix >> 12, p = pix & 4095;
            out[((size_t)b * DD + tid) * HWP + p] = embed[(size_t)s_idx[px] * DD + tid];
        }
    }
}

extern "C" void kernel_launch(void* const* d_in, const int* in_sizes, int n_in,
                              void* d_out, int out_size, void* d_ws, size_t ws_size,
                              hipStream_t stream) {
    const float* z     = (const float*)d_in[0];
    const float* w     = (const float*)d_in[1];
    const float* bias  = (const float*)d_in[2];
    const float* embed = (const float*)d_in[3];
    float* out = (float*)d_out;

    // ws: whS 512K | wcount | wlist 16K
    _Float16* whS = (_Float16*)d_ws;
    int* wcount = (int*)((char*)d_ws + 524288);
    int* wlist  = (int*)((char*)d_ws + 524544);

    hipLaunchKernelGGL(split_w_k,   dim3(128), dim3(256), 0, stream, w, whS, wcount);
    hipLaunchKernelGGL(mfma_gemm_k, dim3(512), dim3(512), 0, stream,
                       z, whS, bias, embed, wcount, wlist, out);
    hipLaunchKernelGGL(fixup_k,     dim3(1024), dim3(256), 0, stream,
                       z, w, bias, embed, wcount, wlist, out);
}